// Round 1
// baseline (276.041 us; speedup 1.0000x reference)
//
#include <hip/hip_runtime.h>

#define LOG2E 1.4426950408889634f
#define LN2   0.6931471805599453f
#define NEGF  (-1.0e30f)

static constexpr int B  = 32;
static constexpr int T  = 1024;   // original time length; we use rows 0..1022
static constexpr int TT = 1023;   // T-1
static constexpr int V  = 1000;
static constexpr int L  = 256;    // padded target length (original); tgt uses cols 1..255
static constexpr int S  = 511;    // 2*255+1 extended states
static constexpr int SP = 512;    // padded state stride
static constexpr int TP = 1024;   // padded rows per batch in E

__device__ __forceinline__ float fexp2(float x) {
#if __has_builtin(__builtin_amdgcn_exp2f)
  return __builtin_amdgcn_exp2f(x);
#else
  return __exp2f(x);
#endif
}
__device__ __forceinline__ float flog2(float x) {
#if __has_builtin(__builtin_amdgcn_logf)
  return __builtin_amdgcn_logf(x);
#else
  return __log2f(x);
#endif
}

// log2-domain logsumexp of 2/3 terms, plus emit
__device__ __forceinline__ float lse2f(float x, float y, float e) {
  float m = fmaxf(x, y);
  return m + flog2(fexp2(x - m) + fexp2(y - m)) + e;
}
__device__ __forceinline__ float lse3f(float x, float y, float z, float e) {
  float m = fmaxf(fmaxf(x, y), z);
  return m + flog2(fexp2(x - m) + fexp2(y - m) + fexp2(z - m)) + e;
}

// ---------------- K0: target lengths from padding mask -------------------
// Handles mask stored as 1-byte bools (numpy bool) or as int32 0/1.
// Byte interpretation of a bool-layout batch gives a count in [130,256];
// byte interpretation of an int32-layout batch gives <= 64. Only if the
// byte count is implausible do we touch the int32 interpretation (which is
// only in-bounds when the buffer really is int32).
__global__ void k_tlen(const unsigned char* __restrict__ maskb,
                       int* __restrict__ tlen) {
  int b = blockIdx.x;
  int lane = threadIdx.x;
  int ca = 0;
  for (int k = lane; k < L; k += 64) ca += (maskb[b * L + k] != 0) ? 1 : 0;
  for (int o = 32; o >= 1; o >>= 1) ca += __shfl_xor(ca, o, 64);
  int cnt = ca;
  if (ca < 130) {  // wave-uniform: layout must be int32
    const int* mi = (const int*)maskb;
    int cb = 0;
    for (int k = lane; k < L; k += 64) cb += (mi[b * L + k] != 0) ? 1 : 0;
    for (int o = 32; o >= 1; o >>= 1) cb += __shfl_xor(cb, o, 64);
    cnt = cb;
  }
  if (lane == 0) tlen[b] = cnt - 1;
}

// ---------------- K1: fused log-softmax denom + emit gather --------------
// One block per (b,t) row. E[b][t][s] = logp2[b][t][ext[s]] (log2 domain),
// NEG for invalid states.
__global__ __launch_bounds__(256) void k_emit(const float* __restrict__ logits,
                                              const int* __restrict__ targets,
                                              const int* __restrict__ tlenp,
                                              float* __restrict__ E) {
  __shared__ float yrow[1000];
  __shared__ float smx[4];
  __shared__ float ssm[4];
  int bid = blockIdx.x;
  int b = bid / TT;
  int t = bid - b * TT;
  int tid = threadIdx.x;

  const float4* row = reinterpret_cast<const float4*>(logits + ((size_t)b * T + t) * V);
  float4 vv = make_float4(0.f, 0.f, 0.f, 0.f);
  float vmax = -3.402823466e38f;
  if (tid < 250) {  // 1000 = 250 * 4 exactly
    vv = row[tid];
    vv.x *= LOG2E; vv.y *= LOG2E; vv.z *= LOG2E; vv.w *= LOG2E;
    yrow[4 * tid + 0] = vv.x;
    yrow[4 * tid + 1] = vv.y;
    yrow[4 * tid + 2] = vv.z;
    yrow[4 * tid + 3] = vv.w;
    vmax = fmaxf(fmaxf(vv.x, vv.y), fmaxf(vv.z, vv.w));
  }
  for (int o = 32; o >= 1; o >>= 1) vmax = fmaxf(vmax, __shfl_xor(vmax, o, 64));
  int wid = tid >> 6;
  if ((tid & 63) == 0) smx[wid] = vmax;
  __syncthreads();
  float my = fmaxf(fmaxf(smx[0], smx[1]), fmaxf(smx[2], smx[3]));
  float ps = 0.0f;
  if (tid < 250) {
    ps = fexp2(vv.x - my) + fexp2(vv.y - my) + fexp2(vv.z - my) + fexp2(vv.w - my);
  }
  for (int o = 32; o >= 1; o >>= 1) ps += __shfl_xor(ps, o, 64);
  if ((tid & 63) == 0) ssm[wid] = ps;
  __syncthreads();
  float lse2 = my + flog2(ssm[0] + ssm[1] + ssm[2] + ssm[3]);

  int tl = tlenp[b];
  int smax = 2 * tl + 1;  // valid: s < smax
  float* Erow = E + ((size_t)b * TP + t) * SP;
#pragma unroll
  for (int r = 0; r < 2; ++r) {
    int s = tid + 256 * r;
    float e;
    if (s >= S) {
      e = NEGF;  // s == 511 pad
    } else {
      int idx = (s & 1) ? targets[b * L + ((s + 1) >> 1)] : 0;  // blank = 0
      float val = yrow[idx] - lse2;
      e = (s < smax) ? val : NEGF;
    }
    Erow[s] = e;
  }
}

// ---------------- K2: serial CTC alpha recurrence ------------------------
// One wave per batch; lane l owns states 8l..8l+7. Single shfl per step,
// no barriers. Emit rows prefetched 4 steps deep.
__global__ __launch_bounds__(64) void k_ctc(const float* __restrict__ E,
                                            const int* __restrict__ targets,
                                            const int* __restrict__ tlenp,
                                            float* __restrict__ lossb) {
  const int b = blockIdx.x;
  const int lane = threadIdx.x;
  const int s0 = lane << 3;
  const int* tg = targets + b * L;

  // skip-allowed flags for odd states (additive: 0 or NEG)
  float f1 = NEGF, f3 = NEGF, f5 = NEGF, f7 = NEGF;
  {
    int s = s0 + 1;
    if (s >= 3) f1 = (tg[(s + 1) >> 1] != tg[(s - 1) >> 1]) ? 0.0f : NEGF;
    s = s0 + 3;
    f3 = (tg[(s + 1) >> 1] != tg[(s - 1) >> 1]) ? 0.0f : NEGF;
    s = s0 + 5;
    f5 = (tg[(s + 1) >> 1] != tg[(s - 1) >> 1]) ? 0.0f : NEGF;
    s = s0 + 7;
    if (s < S) f7 = (tg[(s + 1) >> 1] != tg[(s - 1) >> 1]) ? 0.0f : NEGF;
  }

  const float* Eb = E + (size_t)b * TP * SP + s0;
  const float4* Ep = reinterpret_cast<const float4*>(Eb);  // row r -> Ep[r*128], Ep[r*128+1]

  // alpha init from t=0: only s=0,1 live
  float a0 = (lane == 0) ? Eb[0] : NEGF;
  float a1 = (lane == 0) ? Eb[1] : NEGF;
  float a2 = NEGF, a3 = NEGF, a4 = NEGF, a5 = NEGF, a6 = NEGF, a7 = NEGF;

  float4 P0a = Ep[1 * 128], P0b = Ep[1 * 128 + 1];
  float4 P1a = Ep[2 * 128], P1b = Ep[2 * 128 + 1];
  float4 P2a = Ep[3 * 128], P2b = Ep[3 * 128 + 1];
  float4 P3a = Ep[4 * 128], P3b = Ep[4 * 128 + 1];

#define STEP(EL, EH)                                            \
  do {                                                          \
    float n7 = __shfl_up(a7, 1, 64);                            \
    n7 = (lane == 0) ? NEGF : n7;                               \
    float t0 = lse2f(a0, n7, (EL).x);                           \
    float t1 = lse3f(a1, a0, n7 + f1, (EL).y);                  \
    float t2 = lse2f(a2, a1, (EL).z);                           \
    float t3 = lse3f(a3, a2, a1 + f3, (EL).w);                  \
    float t4 = lse2f(a4, a3, (EH).x);                           \
    float t5 = lse3f(a5, a4, a3 + f5, (EH).y);                  \
    float t6 = lse2f(a6, a5, (EH).z);                           \
    float t7 = lse3f(a7, a6, a5 + f7, (EH).w);                  \
    a0 = t0; a1 = t1; a2 = t2; a3 = t3;                         \
    a4 = t4; a5 = t5; a6 = t6; a7 = t7;                         \
  } while (0)

  int t = 1;
#pragma unroll 1
  for (int it = 0; it < 255; ++it) {  // steps t..t+3, prefetch t+4..t+7
    const float4* q = Ep + (t + 4) * 128;
    float4 q0a = q[0],       q0b = q[1];
    float4 q1a = q[128],     q1b = q[129];
    float4 q2a = q[256],     q2b = q[257];
    float4 q3a = q[384],     q3b = q[385];
    STEP(P0a, P0b);
    STEP(P1a, P1b);
    STEP(P2a, P2b);
    STEP(P3a, P3b);
    P0a = q0a; P0b = q0b; P1a = q1a; P1b = q1b;
    P2a = q2a; P2b = q2b; P3a = q3a; P3b = q3b;
    t += 4;
  }
  STEP(P0a, P0b);  // t = 1021
  STEP(P1a, P1b);  // t = 1022
#undef STEP

  __shared__ float sal[SP];
  sal[s0 + 0] = a0; sal[s0 + 1] = a1; sal[s0 + 2] = a2; sal[s0 + 3] = a3;
  sal[s0 + 4] = a4; sal[s0 + 5] = a5; sal[s0 + 6] = a6; sal[s0 + 7] = a7;
  __syncthreads();
  if (lane == 0) {
    int tl = tlenp[b];
    int i1 = 2 * tl;
    float l1 = sal[i1];
    float l2 = (tl > 0) ? sal[(i1 > 0 ? i1 : 1) - 1] : NEGF;
    float m = fmaxf(l1, l2);
    float loss2 = -(m + flog2(fexp2(l1 - m) + fexp2(l2 - m)));
    float loss = loss2 * LN2;            // back to natural-log domain
    if (loss > 1e20f) loss = 0.0f;       // zero_infinity
    int dv = (tl > 0) ? tl : 1;
    lossb[b] = loss / (float)dv;
  }
}

// ---------------- K3: deterministic mean ---------------------------------
__global__ void k_mean(const float* __restrict__ lossb, float* __restrict__ out) {
  int lane = threadIdx.x;
  float v = (lane < B) ? lossb[lane] : 0.0f;
  for (int o = 32; o >= 1; o >>= 1) v += __shfl_xor(v, o, 64);
  if (lane == 0) out[0] = v / (float)B;
}

extern "C" void kernel_launch(void* const* d_in, const int* in_sizes, int n_in,
                              void* d_out, int out_size, void* d_ws, size_t ws_size,
                              hipStream_t stream) {
  const float* logits = (const float*)d_in[0];
  const int* targets = (const int*)d_in[1];
  const unsigned char* mask = (const unsigned char*)d_in[2];

  char* ws = (char*)d_ws;
  int* tlen = (int*)ws;                 // 32 ints
  float* lossb = (float*)(ws + 128);    // 32 floats
  float* E = (float*)(ws + 256);        // 32*1024*512 floats (+2KB prefetch slack)

  k_tlen<<<B, 64, 0, stream>>>(mask, tlen);
  k_emit<<<B * TT, 256, 0, stream>>>(logits, targets, tlen, E);
  k_ctc<<<B, 64, 0, stream>>>(E, targets, tlen, lossb);
  k_mean<<<1, 64, 0, stream>>>(lossb, (float*)d_out);
}

// Round 3
// 163.301 us; speedup vs baseline: 1.6904x; 1.6904x over previous
//
#include <hip/hip_runtime.h>

#define LOG2E 1.4426950408889634f
#define LN2   0.6931471805599453
#define NEGF  (-1.0e30f)

static constexpr int B  = 32;
static constexpr int T  = 1024;   // original time length; we use rows 0..1022
static constexpr int TT = 1023;   // T-1
static constexpr int V  = 1000;
static constexpr int L  = 256;    // padded target length; labels used are cols 1..255
static constexpr int S  = 511;    // 2*255+1 extended states (valid s: 0..510)
static constexpr int SP = 512;    // padded state stride (slot 511 carries g, zeroed later)
static constexpr int TP = 1024;   // padded rows per batch in E

__device__ __forceinline__ float fexp2(float x) {
#if __has_builtin(__builtin_amdgcn_exp2f)
  return __builtin_amdgcn_exp2f(x);
#else
  return exp2f(x);
#endif
}
__device__ __forceinline__ float flog2(float x) {
#if __has_builtin(__builtin_amdgcn_logf)
  return __builtin_amdgcn_logf(x);   // v_log_f32 = log base 2
#else
  return log2f(x);
#endif
}

// ---------------- K0: target lengths from padding mask -------------------
__global__ void k_tlen(const unsigned char* __restrict__ maskb,
                       int* __restrict__ tlen) {
  int b = blockIdx.x;
  int lane = threadIdx.x;
  int ca = 0;
  for (int k = lane; k < L; k += 64) ca += (maskb[b * L + k] != 0) ? 1 : 0;
  for (int o = 32; o >= 1; o >>= 1) ca += __shfl_xor(ca, o, 64);
  int cnt = ca;
  if (ca < 130) {  // wave-uniform: layout must be int32
    const int* mi = (const int*)maskb;
    int cb = 0;
    for (int k = lane; k < L; k += 64) cb += (mi[b * L + k] != 0) ? 1 : 0;
    for (int o = 32; o >= 1; o >>= 1) cb += __shfl_xor(cb, o, 64);
    cnt = cb;
  }
  if (lane == 0) tlen[b] = cnt - 1;
}

// ---------------- K1: fused softmax-scale + emit gather ------------------
// E[b][t][s] = 2^(y[ext_s] - rowmax)  (scaled probability, <=1), 0 invalid.
// Slot 511 holds g_t = rowmax - log2-denominator (log2 domain correction).
__global__ __launch_bounds__(256) void k_emit(const float* __restrict__ logits,
                                              const int* __restrict__ targets,
                                              const int* __restrict__ tlenp,
                                              float* __restrict__ E) {
  __shared__ float yrow[1000];
  __shared__ float smx[4];
  __shared__ float ssm[4];
  int bid = blockIdx.x;
  int b = bid / TT;
  int t = bid - b * TT;
  int tid = threadIdx.x;

  const float4* row = reinterpret_cast<const float4*>(logits + ((size_t)b * T + t) * V);
  float4 vv = make_float4(0.f, 0.f, 0.f, 0.f);
  float vmax = -3.402823466e38f;
  if (tid < 250) {  // 1000 = 250 * 4 exactly
    vv = row[tid];
    vv.x *= LOG2E; vv.y *= LOG2E; vv.z *= LOG2E; vv.w *= LOG2E;
    yrow[4 * tid + 0] = vv.x;
    yrow[4 * tid + 1] = vv.y;
    yrow[4 * tid + 2] = vv.z;
    yrow[4 * tid + 3] = vv.w;
    vmax = fmaxf(fmaxf(vv.x, vv.y), fmaxf(vv.z, vv.w));
  }
  for (int o = 32; o >= 1; o >>= 1) vmax = fmaxf(vmax, __shfl_xor(vmax, o, 64));
  int wid = tid >> 6;
  if ((tid & 63) == 0) smx[wid] = vmax;
  __syncthreads();
  float my = fmaxf(fmaxf(smx[0], smx[1]), fmaxf(smx[2], smx[3]));
  float ps = 0.0f;
  if (tid < 250) {
    ps = fexp2(vv.x - my) + fexp2(vv.y - my) + fexp2(vv.z - my) + fexp2(vv.w - my);
  }
  for (int o = 32; o >= 1; o >>= 1) ps += __shfl_xor(ps, o, 64);
  if ((tid & 63) == 0) ssm[wid] = ps;
  __syncthreads();
  float g = -flog2(ssm[0] + ssm[1] + ssm[2] + ssm[3]);  // = rowmax - lse2

  int tl = tlenp[b];
  int smax = 2 * tl + 1;  // valid: s < smax
  float* Erow = E + ((size_t)b * TP + t) * SP;
#pragma unroll
  for (int r = 0; r < 2; ++r) {
    int s = tid + 256 * r;
    float e;
    if (s == S) {
      e = g;  // stash per-row log2 correction in the pad slot
    } else {
      int idx = (s & 1) ? targets[b * L + ((s + 1) >> 1)] : 0;  // blank = 0
      float val = fexp2(yrow[idx] - my);
      e = (s < smax) ? val : 0.0f;
    }
    Erow[s] = e;
  }
}

// ---------------- K1b: per-batch sum of g; zero the pad slot -------------
__global__ void k_gsum(float* __restrict__ E, double* __restrict__ GS) {
  int b = blockIdx.x;
  int lane = threadIdx.x;
  double s = 0.0;
  for (int k = lane; k < TT; k += 64) {
    float* p = E + ((size_t)b * TP + k) * SP + 511;
    s += (double)(*p);
    *p = 0.0f;
  }
  for (int o = 32; o >= 1; o >>= 1) s += __shfl_xor(s, o, 64);
  if (lane == 0) GS[b] = s;
}

// ---------------- K2: CTC alpha recurrence, fp64 prob domain -------------
// One wave per batch; lane l owns states 8l..8l+7. Double-buffered emit
// prefetch (8 rows/set). Exact pow2 rescale every 32 steps.
__global__ __launch_bounds__(64) void k_ctc(const float* __restrict__ E,
                                            const int* __restrict__ targets,
                                            const int* __restrict__ tlenp,
                                            const double* __restrict__ GS,
                                            float* __restrict__ lossb) {
  const int b = blockIdx.x;
  const int lane = threadIdx.x;
  const int s0 = lane << 3;
  const int* tg = targets + b * L;

  // skip-allowed multipliers for odd states (1.0 or 0.0)
  double f1 = 0.0, f3, f5, f7 = 0.0;
  {
    int s = s0 + 1;
    if (s >= 3) f1 = (tg[(s + 1) >> 1] != tg[(s - 1) >> 1]) ? 1.0 : 0.0;
    s = s0 + 3;
    f3 = (tg[(s + 1) >> 1] != tg[(s - 1) >> 1]) ? 1.0 : 0.0;
    s = s0 + 5;
    f5 = (tg[(s + 1) >> 1] != tg[(s - 1) >> 1]) ? 1.0 : 0.0;
    s = s0 + 7;
    if (s < S) f7 = (tg[(s + 1) >> 1] != tg[(s - 1) >> 1]) ? 1.0 : 0.0;
  }

  const float* E0 = E + (size_t)b * TP * SP;
  const float4* Ep = reinterpret_cast<const float4*>(E0 + s0);  // row r: Ep[r*128], Ep[r*128+1]

  // alpha init from t=0: only s=0,1 live
  double a0 = (lane == 0) ? (double)E0[0] : 0.0;
  double a1 = (lane == 0) ? (double)E0[1] : 0.0;
  double a2 = 0.0, a3 = 0.0, a4 = 0.0, a5 = 0.0, a6 = 0.0, a7 = 0.0;
  int lsacc = 0;

#define STEPD(EL, EH)                                           \
  do {                                                          \
    double n7 = __shfl_up(a7, 1, 64);                           \
    n7 = (lane == 0) ? 0.0 : n7;                                \
    double e0 = (double)(EL).x, e1 = (double)(EL).y;            \
    double e2 = (double)(EL).z, e3 = (double)(EL).w;            \
    double e4 = (double)(EH).x, e5 = (double)(EH).y;            \
    double e6 = (double)(EH).z, e7 = (double)(EH).w;            \
    double t7 = fma(f7, a5, a6 + a7) * e7;                      \
    double t0 = (a0 + n7) * e0;                                 \
    double t1 = fma(f1, n7, a0 + a1) * e1;                      \
    double t2 = (a1 + a2) * e2;                                 \
    double t3 = fma(f3, a1, a2 + a3) * e3;                      \
    double t4 = (a3 + a4) * e4;                                 \
    double t5 = fma(f5, a3, a4 + a5) * e5;                      \
    double t6 = (a5 + a6) * e6;                                 \
    a0 = t0; a1 = t1; a2 = t2; a3 = t3;                         \
    a4 = t4; a5 = t5; a6 = t6; a7 = t7;                         \
  } while (0)

#define LOAD8(P, r0)                                            \
  do {                                                          \
    const float4* q = Ep + (size_t)(r0) * 128;                  \
    P##0a = q[0];   P##0b = q[1];                               \
    P##1a = q[128]; P##1b = q[129];                             \
    P##2a = q[256]; P##2b = q[257];                             \
    P##3a = q[384]; P##3b = q[385];                             \
    P##4a = q[512]; P##4b = q[513];                             \
    P##5a = q[640]; P##5b = q[641];                             \
    P##6a = q[768]; P##6b = q[769];                             \
    P##7a = q[896]; P##7b = q[897];                             \
  } while (0)

#define PROC8(P)                                                \
  do {                                                          \
    STEPD(P##0a, P##0b); STEPD(P##1a, P##1b);                   \
    STEPD(P##2a, P##2b); STEPD(P##3a, P##3b);                   \
    STEPD(P##4a, P##4b); STEPD(P##5a, P##5b);                   \
    STEPD(P##6a, P##6b); STEPD(P##7a, P##7b);                   \
  } while (0)

// exact pow2 rescale: u32 max of hi-words (alphas >= 0) -> exponent
#define RESCALE()                                               \
  do {                                                          \
    int h0 = __double2hiint(a0), h1 = __double2hiint(a1);       \
    int h2 = __double2hiint(a2), h3 = __double2hiint(a3);       \
    int h4 = __double2hiint(a4), h5 = __double2hiint(a5);       \
    int h6 = __double2hiint(a6), h7 = __double2hiint(a7);       \
    int m = max(max(max(h0, h1), max(h2, h3)),                  \
                max(max(h4, h5), max(h6, h7)));                 \
    m = max(m, __shfl_xor(m, 1, 64));                           \
    m = max(m, __shfl_xor(m, 2, 64));                           \
    m = max(m, __shfl_xor(m, 4, 64));                           \
    m = max(m, __shfl_xor(m, 8, 64));                           \
    m = max(m, __shfl_xor(m, 16, 64));                          \
    m = max(m, __shfl_xor(m, 32, 64));                          \
    int e = m >> 20;                                            \
    int sh = 1022 - e;                                          \
    a0 = ldexp(a0, sh); a1 = ldexp(a1, sh);                     \
    a2 = ldexp(a2, sh); a3 = ldexp(a3, sh);                     \
    a4 = ldexp(a4, sh); a5 = ldexp(a5, sh);                     \
    a6 = ldexp(a6, sh); a7 = ldexp(a7, sh);                     \
    lsacc += e - 1022;                                          \
  } while (0)

  float4 A0a, A0b, A1a, A1b, A2a, A2b, A3a, A3b;
  float4 A4a, A4b, A5a, A5b, A6a, A6b, A7a, A7b;
  float4 B0a, B0b, B1a, B1b, B2a, B2b, B3a, B3b;
  float4 B4a, B4b, B5a, B5b, B6a, B6b, B7a, B7b;

  LOAD8(A, 1);   // rows 1..8
  LOAD8(B, 9);   // rows 9..16

  int t = 1;
#pragma unroll 1
  for (int it = 0; it < 63; ++it) {
    if ((it & 1) == 0) RESCALE();
    PROC8(A);            // rows t..t+7
    LOAD8(A, t + 16);    // rows t+16..t+23
    PROC8(B);            // rows t+8..t+15
    LOAD8(B, t + 24);    // rows t+24..t+31
    t += 16;
  }
  // t = 1009: A holds rows 1009..1016, B holds 1017..1024
  PROC8(A);                                        // -> t=1016 done
  STEPD(B0a, B0b); STEPD(B1a, B1b); STEPD(B2a, B2b);
  STEPD(B3a, B3b); STEPD(B4a, B4b); STEPD(B5a, B5b);  // rows 1017..1022
#undef STEPD
#undef LOAD8
#undef PROC8
#undef RESCALE

  __shared__ double sal[SP];
  sal[s0 + 0] = a0; sal[s0 + 1] = a1; sal[s0 + 2] = a2; sal[s0 + 3] = a3;
  sal[s0 + 4] = a4; sal[s0 + 5] = a5; sal[s0 + 6] = a6; sal[s0 + 7] = a7;
  __syncthreads();
  if (lane == 0) {
    int tl = tlenp[b];
    int i1 = 2 * tl;
    double p = sal[i1] + sal[(i1 > 0 ? i1 : 1) - 1];
    // log2(p) via exponent extraction + f32 log of mantissa
    int hi = __double2hiint(p);
    int ep = (hi >> 20) - 1023;
    double pm = ldexp(p, -ep);          // in [1,2) for normal p
    float lm = flog2((float)pm);
    double loss2 = -((double)lm + (double)ep + (double)lsacc + GS[b]);
    float loss = (float)(loss2 * LN2);  // back to natural log
    if (!(loss <= 1e20f)) loss = 0.0f;  // zero_infinity (inf/nan -> 0)
    int dv = (tl > 0) ? tl : 1;
    lossb[b] = loss / (float)dv;
  }
}

// ---------------- K3: deterministic mean ---------------------------------
__global__ void k_mean(const float* __restrict__ lossb, float* __restrict__ out) {
  int lane = threadIdx.x;
  float v = (lane < B) ? lossb[lane] : 0.0f;
  for (int o = 32; o >= 1; o >>= 1) v += __shfl_xor(v, o, 64);
  if (lane == 0) out[0] = v / (float)B;
}

extern "C" void kernel_launch(void* const* d_in, const int* in_sizes, int n_in,
                              void* d_out, int out_size, void* d_ws, size_t ws_size,
                              hipStream_t stream) {
  const float* logits = (const float*)d_in[0];
  const int* targets = (const int*)d_in[1];
  const unsigned char* mask = (const unsigned char*)d_in[2];

  char* ws = (char*)d_ws;
  int* tlen = (int*)ws;                  // [0,128)
  float* lossb = (float*)(ws + 128);     // [128,256)
  double* GS = (double*)(ws + 256);      // [256,512)
  float* E = (float*)(ws + 512);         // 32*1024*512 f32 = 64MB (+2KB prefetch slack)

  k_tlen<<<B, 64, 0, stream>>>(mask, tlen);
  k_emit<<<B * TT, 256, 0, stream>>>(logits, targets, tlen, E);
  k_gsum<<<B, 64, 0, stream>>>(E, GS);
  k_ctc<<<B, 64, 0, stream>>>(E, targets, tlen, GS, lossb);
  k_mean<<<1, 64, 0, stream>>>(lossb, (float*)d_out);
}

// Round 4
// 126.399 us; speedup vs baseline: 2.1839x; 1.2919x over previous
//
#include <hip/hip_runtime.h>

#define LOG2E 1.4426950408889634f
#define LN2   0.6931471805599453

static constexpr int B  = 32;
static constexpr int T  = 1024;   // original time length; we use rows 0..1022
static constexpr int TT = 1023;   // T-1
static constexpr int V  = 1000;
static constexpr int L  = 256;    // padded target length; labels used are cols 1..255
static constexpr int S  = 511;    // 2*255+1 extended states (valid s: 0..510)
static constexpr int SP = 512;    // padded state stride (slot 511 == 0.0f)
static constexpr int TP = 1024;   // padded rows per batch in E

__device__ __forceinline__ float fexp2(float x) {
#if __has_builtin(__builtin_amdgcn_exp2f)
  return __builtin_amdgcn_exp2f(x);
#else
  return exp2f(x);
#endif
}
__device__ __forceinline__ float flog2(float x) {
#if __has_builtin(__builtin_amdgcn_logf)
  return __builtin_amdgcn_logf(x);   // v_log_f32 = log base 2
#else
  return log2f(x);
#endif
}

// ---- DPP helpers (VALU cross-lane; no LDS) ------------------------------
#if __has_builtin(__builtin_amdgcn_update_dpp)
#define HAVE_DPP 1
// wave_shr1: lane i <- lane i-1; lane 0 <- 0 (bound_ctrl)
__device__ __forceinline__ float shr1f(float x) {
  int r = __builtin_amdgcn_update_dpp(0, __float_as_int(x), 0x138, 0xf, 0xf, true);
  return __int_as_float(r);
}
__device__ __forceinline__ int dppmax_step(int m, const int ctrl) {
  int t;
  switch (ctrl) {  // ctrl must be a literal per call site; switch keeps constants
    case 0x111: t = __builtin_amdgcn_update_dpp(0, m, 0x111, 0xf, 0xf, true); break;
    case 0x112: t = __builtin_amdgcn_update_dpp(0, m, 0x112, 0xf, 0xf, true); break;
    case 0x114: t = __builtin_amdgcn_update_dpp(0, m, 0x114, 0xf, 0xf, true); break;
    case 0x118: t = __builtin_amdgcn_update_dpp(0, m, 0x118, 0xf, 0xf, true); break;
    case 0x142: t = __builtin_amdgcn_update_dpp(0, m, 0x142, 0xf, 0xf, true); break;
    default:    t = __builtin_amdgcn_update_dpp(0, m, 0x143, 0xf, 0xf, true); break;
  }
  return max(m, t);
}
// wave-max of nonneg int across 64 lanes; result valid in lane 63
__device__ __forceinline__ int wavemax_to_sgpr(int m) {
  m = dppmax_step(m, 0x111);  // row_shr:1
  m = dppmax_step(m, 0x112);  // row_shr:2
  m = dppmax_step(m, 0x114);  // row_shr:4
  m = dppmax_step(m, 0x118);  // row_shr:8  -> lane15/31/47/63 = row max
  m = dppmax_step(m, 0x142);  // row_bcast15
  m = dppmax_step(m, 0x143);  // row_bcast31 -> lane63 = wave max
  return __builtin_amdgcn_readlane(m, 63);
}
#else
#define HAVE_DPP 0
__device__ __forceinline__ float shr1f(float x) {
  float r = __shfl_up(x, 1, 64);
  return (threadIdx.x & 63) == 0 ? 0.0f : r;
}
__device__ __forceinline__ int wavemax_to_sgpr(int m) {
  for (int o = 32; o >= 1; o >>= 1) m = max(m, __shfl_xor(m, o, 64));
  return m;
}
#endif

// ---------------- K0: target lengths from padding mask -------------------
__global__ void k_tlen(const unsigned char* __restrict__ maskb,
                       int* __restrict__ tlen) {
  int b = blockIdx.x;
  int lane = threadIdx.x;
  int ca = 0;
  for (int k = lane; k < L; k += 64) ca += (maskb[b * L + k] != 0) ? 1 : 0;
  for (int o = 32; o >= 1; o >>= 1) ca += __shfl_xor(ca, o, 64);
  int cnt = ca;
  if (ca < 130) {  // wave-uniform: layout must be int32
    const int* mi = (const int*)maskb;
    int cb = 0;
    for (int k = lane; k < L; k += 64) cb += (mi[b * L + k] != 0) ? 1 : 0;
    for (int o = 32; o >= 1; o >>= 1) cb += __shfl_xor(cb, o, 64);
    cnt = cb;
  }
  if (lane == 0) tlen[b] = cnt - 1;
}

// ---------------- K1: fused softmax-scale + emit gather ------------------
// E[b][t][s] = 2^(y[ext_s] - rowmax) in f32 (<=1), 0 for invalid; slot 511 = 0.
// G[b][t] = rowmax - log2(sum 2^(y-rowmax))  (per-row log2 correction).
__global__ __launch_bounds__(256) void k_emit(const float* __restrict__ logits,
                                              const int* __restrict__ targets,
                                              const int* __restrict__ tlenp,
                                              float* __restrict__ E,
                                              float* __restrict__ G) {
  __shared__ float yrow[1000];
  __shared__ float smx[4];
  __shared__ float ssm[4];
  int bid = blockIdx.x;
  int b = bid / TT;
  int t = bid - b * TT;
  int tid = threadIdx.x;

  const float4* row = reinterpret_cast<const float4*>(logits + ((size_t)b * T + t) * V);
  float4 vv = make_float4(0.f, 0.f, 0.f, 0.f);
  float vmax = -3.402823466e38f;
  if (tid < 250) {  // 1000 = 250 * 4 exactly
    vv = row[tid];
    vv.x *= LOG2E; vv.y *= LOG2E; vv.z *= LOG2E; vv.w *= LOG2E;
    yrow[4 * tid + 0] = vv.x;
    yrow[4 * tid + 1] = vv.y;
    yrow[4 * tid + 2] = vv.z;
    yrow[4 * tid + 3] = vv.w;
    vmax = fmaxf(fmaxf(vv.x, vv.y), fmaxf(vv.z, vv.w));
  }
  for (int o = 32; o >= 1; o >>= 1) vmax = fmaxf(vmax, __shfl_xor(vmax, o, 64));
  int wid = tid >> 6;
  if ((tid & 63) == 0) smx[wid] = vmax;
  __syncthreads();
  float my = fmaxf(fmaxf(smx[0], smx[1]), fmaxf(smx[2], smx[3]));
  float ps = 0.0f;
  if (tid < 250) {
    ps = fexp2(vv.x - my) + fexp2(vv.y - my) + fexp2(vv.z - my) + fexp2(vv.w - my);
  }
  for (int o = 32; o >= 1; o >>= 1) ps += __shfl_xor(ps, o, 64);
  if ((tid & 63) == 0) ssm[wid] = ps;
  __syncthreads();
  float g = -flog2(ssm[0] + ssm[1] + ssm[2] + ssm[3]);  // = rowmax - lse2

  int tl = tlenp[b];
  int smax = 2 * tl + 1;  // valid: s < smax
  float* Erow = E + ((size_t)b * TP + t) * SP;
#pragma unroll
  for (int r = 0; r < 2; ++r) {
    int s = tid + 256 * r;
    if (s == S) {
      Erow[s] = 0.0f;
      G[b * TT + t] = g;
    } else {
      int idx = (s & 1) ? targets[b * L + ((s + 1) >> 1)] : 0;  // blank = 0
      float val = fexp2(yrow[idx] - my);
      Erow[s] = (s < smax) ? val : 0.0f;
    }
  }
}

// ---------------- K1b: per-batch sum of G --------------------------------
__global__ void k_gsum(const float* __restrict__ G, double* __restrict__ GS) {
  int b = blockIdx.x;
  int lane = threadIdx.x;
  double s = 0.0;
  for (int k = lane; k < TT; k += 64) s += (double)G[b * TT + k];
  for (int o = 32; o >= 1; o >>= 1) s += __shfl_xor(s, o, 64);
  if (lane == 0) GS[b] = s;
}

// ---------------- K2: CTC alpha recurrence, f32 prob domain --------------
// One wave per batch; lane l owns states 8l..8l+7. DPP wave_shr1 for the
// cross-lane state (no LDS). n7 software-pipelined across steps. Exact pow2
// rescale (wave max -> 2^32) every 8 steps via DPP-tree reduction.
__global__ __launch_bounds__(64) void k_ctc(const float* __restrict__ E,
                                            const int* __restrict__ targets,
                                            const int* __restrict__ tlenp,
                                            const double* __restrict__ GS,
                                            float* __restrict__ lossb) {
  const int b = blockIdx.x;
  const int lane = threadIdx.x;
  const int s0 = lane << 3;
  const int* tg = targets + b * L;

  // skip-allowed multipliers for odd states (1.0f or 0.0f)
  float f1 = 0.0f, f3, f5, f7 = 0.0f;
  {
    int s = s0 + 1;
    if (s >= 3) f1 = (tg[(s + 1) >> 1] != tg[(s - 1) >> 1]) ? 1.0f : 0.0f;
    s = s0 + 3;
    f3 = (tg[(s + 1) >> 1] != tg[(s - 1) >> 1]) ? 1.0f : 0.0f;
    s = s0 + 5;
    f5 = (tg[(s + 1) >> 1] != tg[(s - 1) >> 1]) ? 1.0f : 0.0f;
    s = s0 + 7;
    if (s < S) f7 = (tg[(s + 1) >> 1] != tg[(s - 1) >> 1]) ? 1.0f : 0.0f;
  }

  const float* E0 = E + (size_t)b * TP * SP;
  const float4* Ep = reinterpret_cast<const float4*>(E0 + s0);  // row r: Ep[r*128], Ep[r*128+1]

  // alpha init from t=0: only s=0,1 live
  float a0 = (lane == 0) ? E0[0] : 0.0f;
  float a1 = (lane == 0) ? E0[1] : 0.0f;
  float a2 = 0.f, a3 = 0.f, a4 = 0.f, a5 = 0.f, a6 = 0.f, a7 = 0.f;
  float n7 = 0.0f;  // a7 of lane-1, pipelined across steps
  int lsacc = 0;

// One time step. t7 first, its DPP issued immediately (result used next step).
#define STEPF(EL, EH)                                           \
  do {                                                          \
    float t7 = fmaf(f7, a5, a6 + a7) * (EH).w;                  \
    float n7n = shr1f(t7);                                      \
    float t0 = (a0 + n7) * (EL).x;                              \
    float t1 = fmaf(f1, n7, a0 + a1) * (EL).y;                  \
    float t2 = (a1 + a2) * (EL).z;                              \
    float t3 = fmaf(f3, a1, a2 + a3) * (EL).w;                  \
    float t4 = (a3 + a4) * (EH).x;                              \
    float t5 = fmaf(f5, a3, a4 + a5) * (EH).y;                  \
    float t6 = (a5 + a6) * (EH).z;                              \
    a0 = t0; a1 = t1; a2 = t2; a3 = t3;                         \
    a4 = t4; a5 = t5; a6 = t6; a7 = t7;                         \
    n7 = n7n;                                                   \
  } while (0)

#define LOAD8(P, r0)                                            \
  do {                                                          \
    const float4* q = Ep + (size_t)(r0) * 128;                  \
    P##0a = q[0];   P##0b = q[1];                               \
    P##1a = q[128]; P##1b = q[129];                             \
    P##2a = q[256]; P##2b = q[257];                             \
    P##3a = q[384]; P##3b = q[385];                             \
    P##4a = q[512]; P##4b = q[513];                             \
    P##5a = q[640]; P##5b = q[641];                             \
    P##6a = q[768]; P##6b = q[769];                             \
    P##7a = q[896]; P##7b = q[897];                             \
  } while (0)

// exact pow2 rescale: wave-max alpha -> 2^32 (headroom both ways)
#define RESCALE()                                               \
  do {                                                          \
    int m = max(max(max(__float_as_int(a0), __float_as_int(a1)),\
                    max(__float_as_int(a2), __float_as_int(a3))),\
                max(max(__float_as_int(a4), __float_as_int(a5)),\
                    max(__float_as_int(a6), __float_as_int(a7))));\
    int mw = wavemax_to_sgpr(m);                                \
    int e = mw >> 23;                                           \
    int sh = 159 - e;                                           \
    lsacc += e - 159;                                           \
    a0 = ldexpf(a0, sh); a1 = ldexpf(a1, sh);                   \
    a2 = ldexpf(a2, sh); a3 = ldexpf(a3, sh);                   \
    a4 = ldexpf(a4, sh); a5 = ldexpf(a5, sh);                   \
    a6 = ldexpf(a6, sh); a7 = ldexpf(a7, sh);                   \
    n7 = ldexpf(n7, sh);                                        \
  } while (0)

#define PROC8R(P)                                               \
  do {                                                          \
    RESCALE();                                                  \
    STEPF(P##0a, P##0b); STEPF(P##1a, P##1b);                   \
    STEPF(P##2a, P##2b); STEPF(P##3a, P##3b);                   \
    STEPF(P##4a, P##4b); STEPF(P##5a, P##5b);                   \
    STEPF(P##6a, P##6b); STEPF(P##7a, P##7b);                   \
  } while (0)

  float4 A0a, A0b, A1a, A1b, A2a, A2b, A3a, A3b;
  float4 A4a, A4b, A5a, A5b, A6a, A6b, A7a, A7b;
  float4 B0a, B0b, B1a, B1b, B2a, B2b, B3a, B3b;
  float4 B4a, B4b, B5a, B5b, B6a, B6b, B7a, B7b;

  LOAD8(A, 1);   // rows 1..8
  LOAD8(B, 9);   // rows 9..16

  int t = 1;
#pragma unroll 1
  for (int it = 0; it < 63; ++it) {
    PROC8R(A);           // rows t..t+7
    LOAD8(A, t + 16);    // rows t+16..t+23
    PROC8R(B);           // rows t+8..t+15
    LOAD8(B, t + 24);    // rows t+24..t+31
    t += 16;
  }
  // t = 1009: A holds rows 1009..1016, B holds 1017..1024
  PROC8R(A);                                        // rows 1009..1016
  RESCALE();
  STEPF(B0a, B0b); STEPF(B1a, B1b); STEPF(B2a, B2b);
  STEPF(B3a, B3b); STEPF(B4a, B4b); STEPF(B5a, B5b);  // rows 1017..1022
#undef STEPF
#undef LOAD8
#undef PROC8R
#undef RESCALE

  __shared__ float sal[SP];
  sal[s0 + 0] = a0; sal[s0 + 1] = a1; sal[s0 + 2] = a2; sal[s0 + 3] = a3;
  sal[s0 + 4] = a4; sal[s0 + 5] = a5; sal[s0 + 6] = a6; sal[s0 + 7] = a7;
  __syncthreads();
  if (lane == 0) {
    int tl = tlenp[b];
    int i1 = 2 * tl;
    float p = sal[i1] + sal[(i1 > 0 ? i1 : 1) - 1];
    int hi = __float_as_int(p);
    int ep = (hi >> 23) - 127;
    float pm = ldexpf(p, -ep);          // in [1,2) for normal p
    float lm = flog2(pm);
    double loss2 = -((double)lm + (double)ep + (double)lsacc + GS[b]);
    float loss = (float)(loss2 * LN2);  // back to natural log
    if (!(loss <= 1e20f)) loss = 0.0f;  // zero_infinity (inf/nan -> 0)
    int dv = (tl > 0) ? tl : 1;
    lossb[b] = loss / (float)dv;
  }
}

// ---------------- K3: deterministic mean ---------------------------------
__global__ void k_mean(const float* __restrict__ lossb, float* __restrict__ out) {
  int lane = threadIdx.x;
  float v = (lane < B) ? lossb[lane] : 0.0f;
  for (int o = 32; o >= 1; o >>= 1) v += __shfl_xor(v, o, 64);
  if (lane == 0) out[0] = v / (float)B;
}

extern "C" void kernel_launch(void* const* d_in, const int* in_sizes, int n_in,
                              void* d_out, int out_size, void* d_ws, size_t ws_size,
                              hipStream_t stream) {
  const float* logits = (const float*)d_in[0];
  const int* targets = (const int*)d_in[1];
  const unsigned char* mask = (const unsigned char*)d_in[2];

  char* ws = (char*)d_ws;
  int* tlen = (int*)ws;                  // [0,128)
  float* lossb = (float*)(ws + 128);     // [128,256)
  double* GS = (double*)(ws + 256);      // [256,512)
  float* G = (float*)(ws + 512);         // 32*1023 f32 = 131KB
  float* E = (float*)(ws + 512 + 132 * 1024);  // 32*1024*512 f32 = 64MB (+slack)

  k_tlen<<<B, 64, 0, stream>>>(mask, tlen);
  k_emit<<<B * TT, 256, 0, stream>>>(logits, targets, tlen, E, G);
  k_gsum<<<B, 64, 0, stream>>>(G, GS);
  k_ctc<<<B, 64, 0, stream>>>(E, targets, tlen, GS, lossb);
  k_mean<<<1, 64, 0, stream>>>(lossb, (float*)d_out);
}